// Round 6
// baseline (426.095 us; speedup 1.0000x reference)
//
#include <hip/hip_runtime.h>
#include <math.h>

#define NN 50000
#define NE 800000
#define HID 128
#define NL 3
#define NG 64
#define LAT 64
#define QS 512   // fused qkvs row stride

typedef __attribute__((ext_vector_type(8))) short short8v;
typedef __attribute__((ext_vector_type(4))) short short4v;
typedef __attribute__((ext_vector_type(4))) float f32x4;
typedef __attribute__((ext_vector_type(2))) float f32x2;
typedef __attribute__((ext_vector_type(4))) unsigned u32x4;

__device__ __forceinline__ float bf2f(unsigned short b) {
    unsigned u = ((unsigned)b) << 16;
    return __builtin_bit_cast(float, u);
}
__device__ __forceinline__ unsigned short f2bf(float f) {
    unsigned u = __builtin_bit_cast(unsigned, f);
    u += 0x7FFFu + ((u >> 16) & 1u);   // round-to-nearest-even
    return (unsigned short)(u >> 16);
}
// unpack a dword holding two bf16 into float2 (2 VALU ops, no extracts)
__device__ __forceinline__ f32x2 bfpair(unsigned d) {
    f32x2 o;
    o[0] = __builtin_bit_cast(float, d << 16);
    o[1] = __builtin_bit_cast(float, d & 0xffff0000u);
    return o;
}

// ---------------- pack weights/biases to bf16 + zero-init deg/pooled --------
struct PtrTab { const float* p[13]; };

__global__ __launch_bounds__(256) void pack_all_kernel(
    PtrTab wt, PtrTab bt, short* __restrict__ Wcat, float* __restrict__ bcat,
    int* __restrict__ deg, float* __restrict__ pooled)
{
    int gid = blockIdx.x * 256 + threadIdx.x;          // grid covers 13*16384
    if (gid < 13 * 16384) {
        int slot = gid >> 14, e = gid & 16383;
        Wcat[gid] = (short)f2bf(wt.p[slot][e]);
    }
    if (gid < 13 * 128) {
        int slot = gid >> 7, e = gid & 127;
        bcat[gid] = bt.p[slot][e];
    }
    if (gid < NN) deg[gid] = 0;
    if (gid < NG * HID) pooled[gid] = 0.f;
}

// ---------------- MFMA GEMM: Y[r, j] = sum_k A[r,k]*W[j,k] + bias[j] --------
// NM=4: 64-row blocks, 256 thr, 782 blocks (fixes CU quantization).
// NM=1: 128-row blocks, 128 thr, 391 blocks. CVT=1: fp32 A converted on load.
// Epilogue staged through LDS for coalesced 16B/lane stores.
template<int NM, int CVT>
__global__ __launch_bounds__((NM == 4) ? 256 : 128, 2) void gemm_mfma(
    const void* __restrict__ Av, const short* __restrict__ Wcat,
    const float* __restrict__ bias, short* __restrict__ out, int nrows)
{
    constexpr int NC  = NM * 128;
    constexpr int KST = (NM == 4) ? 2 : 1;   // k stages
    constexpr int KBS = 16 / KST;            // kb (k/8) per stage
    constexpr int WN  = (NM == 4) ? 4 : 1;
    constexpr int WM  = (NM == 4) ? 1 : 2;
    constexpr int NTH = WN * WM * 64;        // 256 / 128
    constexpr int CH  = KBS * NC / NTH;      // short8v chunks per thread per stage
    constexpr int CSTR = NC + 4;             // epilogue LDS row stride (shorts)
    constexpr int QROWS = WM * 16;           // rows per epilogue quarter
    constexpr int CHK = QROWS * (NC / 8) / NTH;  // b128 chunks per thread
    constexpr int SMEM_W = KBS * NC * 8 * 2;
    constexpr int SMEM_C = QROWS * CSTR * 2;
    constexpr int SMEM = (SMEM_W > SMEM_C) ? SMEM_W : SMEM_C;
    __shared__ char smem[SMEM];
    short* Wlds = (short*)smem;
    short* Clds = (short*)smem;

    const short* Ab = (const short*)Av;
    const float* Af = (const float*)Av;

    const int tid  = threadIdx.x;
    const int lane = tid & 63;
    const int wid  = tid >> 6;
    const int wn = wid % WN;
    const int wm = wid / WN;
    const int blockbase = blockIdx.x * (WM * 64);
    const int rbase = blockbase + wm * 64;
    const int r0 = rbase + (lane & 15);
    const int n0 = wn * 128;
    const int lg = lane >> 4;

    f32x4 acc[4][8];
#pragma unroll
    for (int i = 0; i < 4; ++i)
#pragma unroll
        for (int j = 0; j < 8; ++j) acc[i][j] = {0.f, 0.f, 0.f, 0.f};

    const short8v zero8 = {0, 0, 0, 0, 0, 0, 0, 0};

    auto stage = [&](int st) {
#pragma unroll
        for (int c2 = 0; c2 < CH; ++c2) {
            int c = tid + NTH * c2;
            int j = c & (NC - 1);
            int kbl = c / NC;
            int kb = st * KBS + kbl;
            *reinterpret_cast<short8v*>(&Wlds[(kbl * NC + j) * 8]) =
                *reinterpret_cast<const short8v*>(&Wcat[j * HID + kb * 8]);
        }
    };
    auto compute_stage = [&](int s_lo, int s_hi) {
        for (int s = s_lo; s < s_hi; ++s) {
            short8v a[4], b[8];
#pragma unroll
            for (int mf = 0; mf < 4; ++mf) {
                int row = r0 + mf * 16;
                if (CVT) {
                    if (row < nrows) {
                        const float* ap = Af + (size_t)row * HID + s * 32 + lg * 8;
                        float4 f0 = *reinterpret_cast<const float4*>(ap);
                        float4 f1 = *reinterpret_cast<const float4*>(ap + 4);
                        short8v t;
                        t[0] = (short)f2bf(f0.x); t[1] = (short)f2bf(f0.y);
                        t[2] = (short)f2bf(f0.z); t[3] = (short)f2bf(f0.w);
                        t[4] = (short)f2bf(f1.x); t[5] = (short)f2bf(f1.y);
                        t[6] = (short)f2bf(f1.z); t[7] = (short)f2bf(f1.w);
                        a[mf] = t;
                    } else a[mf] = zero8;
                } else {
                    a[mf] = (row < nrows)
                        ? *reinterpret_cast<const short8v*>(&Ab[(size_t)row * HID + s * 32 + lg * 8])
                        : zero8;
                }
            }
            const int kbl = (s - s_lo) * 4 + lg;
#pragma unroll
            for (int nf = 0; nf < 8; ++nf) {
                int slot = kbl * NC + n0 + nf * 16 + (lane & 15);
                b[nf] = *reinterpret_cast<const short8v*>(&Wlds[slot * 8]);
            }
#pragma unroll
            for (int mf = 0; mf < 4; ++mf)
#pragma unroll
                for (int nf = 0; nf < 8; ++nf)
                    acc[mf][nf] = __builtin_amdgcn_mfma_f32_16x16x32_bf16(
                        a[mf], b[nf], acc[mf][nf], 0, 0, 0);
        }
    };

    stage(0);
    __syncthreads();
    compute_stage(0, 4 / KST);
    if (KST == 2) {
        __syncthreads();
        stage(1);
        __syncthreads();
        compute_stage(2, 4);
    }

    // ---- epilogue: 4 quarter passes through LDS, coalesced stores ----
#pragma unroll
    for (int mf = 0; mf < 4; ++mf) {
        __syncthreads();
#pragma unroll
        for (int nf = 0; nf < 8; ++nf) {
            int col = n0 + nf * 16 + (lane & 15);
            float bv = bias[col];
#pragma unroll
            for (int qq = 0; qq < 4; ++qq) {
                int rl = wm * 16 + lg * 4 + qq;
                Clds[rl * CSTR + col] = (short)f2bf(acc[mf][nf][qq] + bv);
            }
        }
        __syncthreads();
#pragma unroll
        for (int i = 0; i < CHK; ++i) {
            int c = tid + NTH * i;
            int rl = c / (NC / 8);
            int ck = c % (NC / 8);
            int grow = blockbase + (rl >> 4) * 64 + mf * 16 + (rl & 15);
            if (grow < nrows)
                *reinterpret_cast<short8v*>(&out[(size_t)grow * NC + ck * 8]) =
                    *reinterpret_cast<const short8v*>(&Clds[rl * CSTR + ck * 8]);
        }
    }
}

// ---------------- CSR build ----------------
__global__ __launch_bounds__(256) void count_deg_kernel(
    const int* __restrict__ dst, int* __restrict__ deg, int ne)
{
    int e = blockIdx.x * 256 + threadIdx.x;
    if (e < ne) atomicAdd(&deg[dst[e]], 1);
}

__global__ __launch_bounds__(1024) void scan1_kernel(
    const int* __restrict__ deg, int* __restrict__ offsets,
    int* __restrict__ bsum, int n)
{
    __shared__ int wsum[16];
    const int tid = threadIdx.x, wid = tid >> 6, lane = tid & 63;
    int i = blockIdx.x * 1024 + tid;
    int val = (i < n) ? deg[i] : 0;
    int x = val;
#pragma unroll
    for (int off = 1; off < 64; off <<= 1) {
        int y = __shfl_up(x, off);
        if (lane >= off) x += y;
    }
    if (lane == 63) wsum[wid] = x;
    __syncthreads();
    if (tid < 16) {
        int w = wsum[tid];
#pragma unroll
        for (int off = 1; off < 16; off <<= 1) {
            int y = __shfl_up(w, off);
            if (tid >= off) w += y;
        }
        wsum[tid] = w;
    }
    __syncthreads();
    int incl = x + (wid ? wsum[wid - 1] : 0);
    if (i < n) offsets[i + 1] = incl;
    if (tid == 1023) bsum[blockIdx.x] = incl;
}

__global__ __launch_bounds__(256) void scan3_kernel(
    const int* __restrict__ deg, int* __restrict__ offsets,
    int* __restrict__ cursor, const int* __restrict__ bsum, int n, int nb)
{
    __shared__ int sx[64];
    const int tid = threadIdx.x;
    if (tid < 64) {
        int vv = (tid < nb) ? bsum[tid] : 0;
        int x = vv;
#pragma unroll
        for (int off = 1; off < 64; off <<= 1) {
            int y = __shfl_up(x, off);
            if (tid >= off) x += y;
        }
        sx[tid] = x - vv;   // exclusive prefix of block sums
    }
    __syncthreads();
    int i = blockIdx.x * 256 + tid;
    if (i >= n) return;
    int incl = offsets[i + 1] + sx[i >> 10];
    offsets[i + 1] = incl;
    cursor[i] = incl - deg[i];
    if (i == 0) offsets[0] = 0;
}

__global__ __launch_bounds__(256) void scatter_kernel(
    const int* __restrict__ src, const int* __restrict__ dst,
    int* __restrict__ cursor, int* __restrict__ csr_src, int ne)
{
    int e = blockIdx.x * 256 + threadIdx.x;
    if (e < ne) {
        int pos = atomicAdd(&cursor[dst[e]], 1);
        csr_src[pos] = src[e];
    }
}

// ---------------- fused attention + skip + ReLU ----------------
// One wave per node; 4 edge slots x 16 lanes; lane owns 8 dims (16B).
// True double-buffer: next batch's K/V loads issued (exec-predicated, no
// waste) before current batch compute. float2 math for packed FMA.
__global__ __launch_bounds__(256) void attn_kernel(
    const short* __restrict__ qkvs, const int* __restrict__ offsets,
    const int* __restrict__ csr_src, short* __restrict__ hout, int nnodes)
{
    int node = (blockIdx.x * 256 + threadIdx.x) >> 6;
    if (node >= nnodes) return;
    const int lane = threadIdx.x & 63;
    const int grp = lane >> 4;        // edge slot 0..3
    const int g   = lane & 15;        // dims 8g..8g+7 (head = g/4)
    const float scale = 0.17677669529663687f; // 1/sqrt(32)
    const short8v zero8 = {0, 0, 0, 0, 0, 0, 0, 0};

    const size_t nb = (size_t)node * QS;
    short8v q8 = *reinterpret_cast<const short8v*>(&qkvs[nb + g * 8]);
    u32x4 qd = __builtin_bit_cast(u32x4, q8);
    f32x2 qf2[4];
#pragma unroll
    for (int i = 0; i < 4; ++i) qf2[i] = bfpair(qd[i]);

    int e0 = offsets[node], e1 = offsets[node + 1];
    float s = 0.f;
    f32x2 acc2[4] = {{0.f, 0.f}, {0.f, 0.f}, {0.f, 0.f}, {0.f, 0.f}};

    const short* kvb = qkvs + 128 + g * 8;   // K base for this lane

    int e = e0 + grp;
    bool va = e < e1, vb = e + 4 < e1;
    int ia = va ? csr_src[e] : 0;
    int ib = vb ? csr_src[e + 4] : 0;
    short8v ka = zero8, xa = zero8, kb = zero8, xb = zero8;
    if (va) { const short* p = kvb + ((unsigned)ia << 9); ka = *(const short8v*)p; xa = *(const short8v*)(p + 128); }
    if (vb) { const short* p = kvb + ((unsigned)ib << 9); kb = *(const short8v*)p; xb = *(const short8v*)(p + 128); }

    while (va) {
        int en = e + 8;
        bool van = en < e1, vbn = en + 4 < e1;
        int ian = van ? csr_src[en] : 0;
        int ibn = vbn ? csr_src[en + 4] : 0;
        short8v kan = zero8, xan = zero8, kbn = zero8, xbn = zero8;
        if (van) { const short* p = kvb + ((unsigned)ian << 9); kan = *(const short8v*)p; xan = *(const short8v*)(p + 128); }
        if (vbn) { const short* p = kvb + ((unsigned)ibn << 9); kbn = *(const short8v*)p; xbn = *(const short8v*)(p + 128); }

        // ---- compute current batch ----
        {
            u32x4 kda = __builtin_bit_cast(u32x4, ka);
            u32x4 kdb = __builtin_bit_cast(u32x4, kb);
            f32x2 pa2 = {0.f, 0.f}, pb2 = {0.f, 0.f};
#pragma unroll
            for (int i = 0; i < 4; ++i) {
                pa2 += qf2[i] * bfpair(kda[i]);
                pb2 += qf2[i] * bfpair(kdb[i]);
            }
            float pa = pa2[0] + pa2[1];
            float pb = pb2[0] + pb2[1];
            pa += __shfl_xor(pa, 1);  pb += __shfl_xor(pb, 1);
            pa += __shfl_xor(pa, 2);  pb += __shfl_xor(pb, 2);
            float aa = va ? fminf(pa * scale, 60.f) : -1e30f;
            float ab = vb ? fminf(pb * scale, 60.f) : -1e30f;
            float wa = __expf(aa);
            float wb = __expf(ab);
            s += wa + wb;
            f32x2 wa2 = {wa, wa}, wb2 = {wb, wb};
            u32x4 xda = __builtin_bit_cast(u32x4, xa);
            u32x4 xdb = __builtin_bit_cast(u32x4, xb);
#pragma unroll
            for (int i = 0; i < 4; ++i)
                acc2[i] += wa2 * bfpair(xda[i]) + wb2 * bfpair(xdb[i]);
        }

        e = en; va = van; vb = vbn;
        ka = kan; xa = xan; kb = kbn; xb = xbn;
    }

    // merge the 4 edge slots (once per node)
#pragma unroll
    for (int off = 16; off <= 32; off <<= 1) {
        s += __shfl_xor(s, off);
#pragma unroll
        for (int i = 0; i < 4; ++i) {
            acc2[i][0] += __shfl_xor(acc2[i][0], off);
            acc2[i][1] += __shfl_xor(acc2[i][1], off);
        }
    }
    float inv = 1.f / (s + 1e-16f);
    short8v sk8 = *reinterpret_cast<const short8v*>(&qkvs[nb + 384 + g * 8]);
    u32x4 skd = __builtin_bit_cast(u32x4, sk8);
    short8v o;
#pragma unroll
    for (int i = 0; i < 4; ++i) {
        f32x2 sk2 = bfpair(skd[i]);
        float o0 = fmaxf(acc2[i][0] * inv + sk2[0], 0.f);
        float o1 = fmaxf(acc2[i][1] * inv + sk2[1], 0.f);
        o[2 * i]     = (short)f2bf(o0);
        o[2 * i + 1] = (short)f2bf(o1);
    }
    *reinterpret_cast<short8v*>(&hout[(size_t)node * HID + g * 8]) = o;
}

// ---------------- pooling over sorted batch (bf16 h) ----------------
__global__ __launch_bounds__(256) void pool_kernel(
    const short* __restrict__ h, const int* __restrict__ batch,
    float* __restrict__ pooled, int nnodes)
{
    const int ROWS = 256;
    int n0 = blockIdx.x * ROWS;
    if (n0 >= nnodes) return;
    int n1 = min(n0 + ROWS, nnodes);
    int rg = threadIdx.x >> 4;      // 16 parallel row streams
    int c8 = threadIdx.x & 15;      // 8 cols each (16B loads)
    float s[8] = {0.f, 0.f, 0.f, 0.f, 0.f, 0.f, 0.f, 0.f};
    int g = -1;
    for (int n = n0 + rg; n < n1; n += 16) {
        int bg = batch[n];
        if (bg != g) {
            if (g >= 0) {
#pragma unroll
                for (int i = 0; i < 8; ++i) {
                    atomicAdd(&pooled[g * HID + c8 * 8 + i], s[i]);
                    s[i] = 0.f;
                }
            }
            g = bg;
        }
        short8v hv = *reinterpret_cast<const short8v*>(&h[(size_t)n * HID + c8 * 8]);
#pragma unroll
        for (int i = 0; i < 8; ++i) s[i] += bf2f((unsigned short)hv[i]);
    }
    if (g >= 0) {
#pragma unroll
        for (int i = 0; i < 8; ++i)
            atomicAdd(&pooled[g * HID + c8 * 8 + i], s[i]);
    }
}

// ---------------- final FC ----------------
__global__ __launch_bounds__(256) void fc_kernel(
    const float* __restrict__ pooled, const float* __restrict__ Wfc,
    const float* __restrict__ bfc, float* __restrict__ out)
{
    int t = blockIdx.x * 256 + threadIdx.x;   // 4096 = G*LAT
    if (t >= NG * LAT) return;
    int g = t >> 6, o = t & 63;
    float sum = bfc[o];
    for (int j = 0; j < HID; ++j)
        sum += pooled[g * HID + j] * Wfc[o * HID + j];
    out[t] = sum;
}

extern "C" void kernel_launch(void* const* d_in, const int* in_sizes, int n_in,
                              void* d_out, int out_size, void* d_ws, size_t ws_size,
                              hipStream_t stream)
{
    const float* x     = (const float*)d_in[0];
    const int*   ei    = (const int*)d_in[1];
    const int*   batch = (const int*)d_in[2];
    const float* Win   = (const float*)d_in[3];
    const float* bin_  = (const float*)d_in[4];
    const float* Wq    = (const float*)d_in[5];
    const float* bq    = (const float*)d_in[6];
    const float* Wk    = (const float*)d_in[7];
    const float* bk    = (const float*)d_in[8];
    const float* Wv    = (const float*)d_in[9];
    const float* bv    = (const float*)d_in[10];
    const float* Wskip = (const float*)d_in[11];
    const float* bskip = (const float*)d_in[12];
    const float* Wfc   = (const float*)d_in[13];
    const float* bfc   = (const float*)d_in[14];
    float* out = (float*)d_out;

    // workspace layout (~76 MB), 256B-aligned chunks
    char* ws = (char*)d_ws;
    auto alloc = [&](size_t bytes) {
        void* p = (void*)ws;
        ws += (bytes + 255) & ~(size_t)255;
        return p;
    };
    short* hb     = (short*)alloc((size_t)NN * HID * 2);
    short* qkvs   = (short*)alloc((size_t)NN * QS * 2);
    short* Wcat   = (short*)alloc((size_t)13 * 16384 * 2);
    float* bcat   = (float*)alloc((size_t)13 * 128 * 4);
    float* pooled = (float*)alloc((size_t)NG * HID * 4);
    int* deg      = (int*)alloc((size_t)NN * 4);
    int* offsets  = (int*)alloc((size_t)(NN + 1) * 4);
    int* cursor   = (int*)alloc((size_t)NN * 4);
    int* bsum     = (int*)alloc((size_t)64 * 4);
    int* csr_src  = (int*)alloc((size_t)NE * 4);

    const int* esrc = ei;
    const int* edst = ei + NE;

    PtrTab wt, bt;
    wt.p[0] = Win; bt.p[0] = bin_;
    for (int l = 0; l < NL; ++l) {
        wt.p[1 + 4 * l] = Wq    + (size_t)l * HID * HID;
        wt.p[2 + 4 * l] = Wk    + (size_t)l * HID * HID;
        wt.p[3 + 4 * l] = Wv    + (size_t)l * HID * HID;
        wt.p[4 + 4 * l] = Wskip + (size_t)l * HID * HID;
        bt.p[1 + 4 * l] = bq    + (size_t)l * HID;
        bt.p[2 + 4 * l] = bk    + (size_t)l * HID;
        bt.p[3 + 4 * l] = bv    + (size_t)l * HID;
        bt.p[4 + 4 * l] = bskip + (size_t)l * HID;
    }

    pack_all_kernel<<<(13 * 16384) / 256, 256, 0, stream>>>(wt, bt, Wcat, bcat, deg, pooled);

    const int egrid = (NE + 255) / 256;
    const int nsb = (NN + 1023) / 1024;   // 49
    count_deg_kernel<<<egrid, 256, 0, stream>>>(edst, deg, NE);
    scan1_kernel<<<nsb, 1024, 0, stream>>>(deg, offsets, bsum, NN);
    scan3_kernel<<<(NN + 255) / 256, 256, 0, stream>>>(deg, offsets, cursor, bsum, NN, nsb);
    scatter_kernel<<<egrid, 256, 0, stream>>>(esrc, edst, cursor, csr_src, NE);

    // input projection: h = x @ Win^T + bin (fp32 A converted on load)
    gemm_mfma<1, 1><<<(NN + 127) / 128, 128, 0, stream>>>(x, Wcat, bcat, hb, NN);

    const int g4 = (NN + 63) / 64;        // 782
    for (int l = 0; l < NL; ++l) {
        gemm_mfma<4, 0><<<g4, 256, 0, stream>>>(
            hb, Wcat + (size_t)(1 + 4 * l) * 16384, bcat + (1 + 4 * l) * 128, qkvs, NN);
        attn_kernel<<<(NN + 3) / 4, 256, 0, stream>>>(qkvs, offsets, csr_src, hb, NN);
    }

    pool_kernel<<<(NN + 255) / 256, 256, 0, stream>>>(hb, batch, pooled, NN);
    fc_kernel<<<16, 256, 0, stream>>>(pooled, Wfc, bfc, out);
}

// Round 7
// 416.495 us; speedup vs baseline: 1.0230x; 1.0230x over previous
//
#include <hip/hip_runtime.h>
#include <math.h>

#define NN 50000
#define NE 800000
#define HID 128
#define NL 3
#define NG 64
#define LAT 64
#define QS 512   // fused qkvs row stride

typedef __attribute__((ext_vector_type(8))) short short8v;
typedef __attribute__((ext_vector_type(4))) short short4v;
typedef __attribute__((ext_vector_type(4))) float f32x4;

__device__ __forceinline__ float bf2f(unsigned short b) {
    unsigned u = ((unsigned)b) << 16;
    return __builtin_bit_cast(float, u);
}
__device__ __forceinline__ unsigned short f2bf(float f) {
    unsigned u = __builtin_bit_cast(unsigned, f);
    u += 0x7FFFu + ((u >> 16) & 1u);   // round-to-nearest-even
    return (unsigned short)(u >> 16);
}

// async global->LDS, 16B per lane. LDS dest must be wave-uniform base + lane*16.
__device__ __forceinline__ void gl_lds16(const void* g, void* l) {
    __builtin_amdgcn_global_load_lds(
        (const __attribute__((address_space(1))) void*)g,
        (__attribute__((address_space(3))) void*)l, 16, 0, 0);
}

// ---------------- pack weights/biases to bf16 + zero-init deg/pooled --------
struct PtrTab { const float* p[13]; };

__global__ __launch_bounds__(256) void pack_all_kernel(
    PtrTab wt, PtrTab bt, short* __restrict__ Wcat, float* __restrict__ bcat,
    int* __restrict__ deg, float* __restrict__ pooled)
{
    int gid = blockIdx.x * 256 + threadIdx.x;          // grid covers 13*16384
    if (gid < 13 * 16384) {
        int slot = gid >> 14, e = gid & 16383;
        Wcat[gid] = (short)f2bf(wt.p[slot][e]);
    }
    if (gid < 13 * 128) {
        int slot = gid >> 7, e = gid & 127;
        bcat[gid] = bt.p[slot][e];
    }
    if (gid < NN) deg[gid] = 0;
    if (gid < NG * HID) pooled[gid] = 0.f;
}

// ---------------- MFMA GEMM: Y[r, j] = sum_k A[r,k]*W[j,k] + bias[j] --------
// NM=4: 128-row blocks, 512 thr, W (128KB) streamed via global_load_lds in a
// 4-phase double-buffered (2x32KB) pipeline: issue phase p+1 loads after the
// A-frag loads of phase p, so vmcnt for A doesn't drain them; barrier drains.
// NM=1: 256-row blocks, 256 thr, single 32KB gload_lds stage. CVT=1: fp32 A.
// Epilogue staged through LDS for coalesced 16B/lane stores.
template<int NM, int CVT>
__global__ __launch_bounds__((NM == 4) ? 512 : 256, 2) void gemm_mfma(
    const void* __restrict__ Av, const short* __restrict__ Wcat,
    const float* __restrict__ bias, short* __restrict__ out, int nrows)
{
    constexpr int NC  = NM * 128;
    constexpr int WN  = (NM == 4) ? 4 : 1;
    constexpr int WM  = (NM == 4) ? 2 : 4;
    constexpr int NTH = WN * WM * 64;        // 512 / 256
    constexpr int BUFS = (NM == 4) ? 16384 : 16384;  // shorts per buffer (32KB)
    constexpr int CSTR = NC + 4;             // epilogue LDS row stride (shorts)
    constexpr int QROWS = WM * 16;           // rows per epilogue quarter
    constexpr int CHK = QROWS * (NC / 8) / NTH;  // b128 chunks per thread
    constexpr int SMEM_W = ((NM == 4) ? 2 * BUFS : BUFS) * 2;
    constexpr int SMEM_C = QROWS * CSTR * 2;
    constexpr int SMEM = (SMEM_W > SMEM_C) ? SMEM_W : SMEM_C;
    __shared__ char smem[SMEM];
    short* Wlds = (short*)smem;
    short* Clds = (short*)smem;

    const short* Ab = (const short*)Av;
    const float* Af = (const float*)Av;

    const int tid  = threadIdx.x;
    const int lane = tid & 63;
    const int wid  = tid >> 6;
    const int wn = wid % WN;
    const int wm = wid / WN;
    const int blockbase = blockIdx.x * (WM * 64);
    const int rbase = blockbase + wm * 64;
    const int r0 = rbase + (lane & 15);
    const int n0 = wn * 128;
    const int lg = lane >> 4;

    f32x4 acc[4][8];
#pragma unroll
    for (int i = 0; i < 4; ++i)
#pragma unroll
        for (int j = 0; j < 8; ++j) acc[i][j] = {0.f, 0.f, 0.f, 0.f};

    const short8v zero8 = {0, 0, 0, 0, 0, 0, 0, 0};

    // ---- A fragment loader for k-phase s ----
    auto load_a = [&](int s, short8v a[4]) {
#pragma unroll
        for (int mf = 0; mf < 4; ++mf) {
            int row = r0 + mf * 16;
            if (CVT) {
                if (row < nrows) {
                    const float* ap = Af + (size_t)row * HID + s * 32 + lg * 8;
                    float4 f0 = *reinterpret_cast<const float4*>(ap);
                    float4 f1 = *reinterpret_cast<const float4*>(ap + 4);
                    short8v t;
                    t[0] = (short)f2bf(f0.x); t[1] = (short)f2bf(f0.y);
                    t[2] = (short)f2bf(f0.z); t[3] = (short)f2bf(f0.w);
                    t[4] = (short)f2bf(f1.x); t[5] = (short)f2bf(f1.y);
                    t[6] = (short)f2bf(f1.z); t[7] = (short)f2bf(f1.w);
                    a[mf] = t;
                } else a[mf] = zero8;
            } else {
                a[mf] = (row < nrows)
                    ? *reinterpret_cast<const short8v*>(&Ab[(size_t)row * HID + s * 32 + lg * 8])
                    : zero8;
            }
        }
    };
    // ---- MFMA for one k-phase: B rows kbl = lg within the given buffer ----
    auto mfma_phase = [&](const short* buf, int kbl, const short8v a[4]) {
        short8v b[8];
#pragma unroll
        for (int nf = 0; nf < 8; ++nf) {
            int slot = kbl * NC + n0 + nf * 16 + (lane & 15);
            b[nf] = *reinterpret_cast<const short8v*>(&buf[slot * 8]);
        }
#pragma unroll
        for (int mf = 0; mf < 4; ++mf)
#pragma unroll
            for (int nf = 0; nf < 8; ++nf)
                acc[mf][nf] = __builtin_amdgcn_mfma_f32_16x16x32_bf16(
                    a[mf], b[nf], acc[mf][nf], 0, 0, 0);
    };

    if (NM == 4) {
        // 4-phase double-buffered W pipeline (phase p holds kb = 4p..4p+3)
        short* buf0 = Wlds;
        short* buf1 = Wlds + BUFS;
        // prologue: stage phase 0
#pragma unroll
        for (int c2 = 0; c2 < 4; ++c2) {
            int c = tid + 512 * c2;
            int j = c & 511;                 // kbl == c2 since NTH == NC == 512
            gl_lds16(&Wcat[j * HID + c2 * 8], &buf0[(size_t)c * 8]);
        }
        __syncthreads();
#pragma unroll
        for (int p = 0; p < 4; ++p) {
            short* cur = (p & 1) ? buf1 : buf0;
            short* nxt = (p & 1) ? buf0 : buf1;
            short8v a[4];
            load_a(p, a);                    // A loads first (older in vmcnt queue)
            if (p < 3) {
#pragma unroll
                for (int c2 = 0; c2 < 4; ++c2) {
                    int c = tid + 512 * c2;
                    int j = c & 511;
                    int kb = (p + 1) * 4 + c2;
                    gl_lds16(&Wcat[j * HID + kb * 8], &nxt[(size_t)c * 8]);
                }
            }
            mfma_phase(cur, lg, a);          // waits A (vmcnt leaves glds in flight)
            __syncthreads();                 // drains glds for next phase
        }
    } else {
        // single 32KB stage (16 kb rows)
#pragma unroll
        for (int c2 = 0; c2 < 8; ++c2) {
            int c = tid + 256 * c2;
            int j = c & 127;
            int kb = c >> 7;                 // wave-constant per chunk
            gl_lds16(&Wcat[j * HID + kb * 8], &Wlds[(size_t)c * 8]);
        }
        __syncthreads();
        for (int s = 0; s < 4; ++s) {
            short8v a[4];
            load_a(s, a);
            mfma_phase(Wlds, s * 4 + lg, a);
        }
    }

    // ---- epilogue: 4 quarter passes through LDS, coalesced stores ----
#pragma unroll
    for (int mf = 0; mf < 4; ++mf) {
        __syncthreads();
#pragma unroll
        for (int nf = 0; nf < 8; ++nf) {
            int col = n0 + nf * 16 + (lane & 15);
            float bv = bias[col];
#pragma unroll
            for (int qq = 0; qq < 4; ++qq) {
                int rl = wm * 16 + lg * 4 + qq;
                Clds[rl * CSTR + col] = (short)f2bf(acc[mf][nf][qq] + bv);
            }
        }
        __syncthreads();
#pragma unroll
        for (int i = 0; i < CHK; ++i) {
            int c = tid + NTH * i;
            int rl = c / (NC / 8);
            int ck = c % (NC / 8);
            int grow = blockbase + (rl >> 4) * 64 + mf * 16 + (rl & 15);
            if (grow < nrows)
                *reinterpret_cast<short8v*>(&out[(size_t)grow * NC + ck * 8]) =
                    *reinterpret_cast<const short8v*>(&Clds[rl * CSTR + ck * 8]);
        }
    }
}

// ---------------- CSR build ----------------
__global__ __launch_bounds__(256) void count_deg_kernel(
    const int* __restrict__ dst, int* __restrict__ deg, int ne)
{
    int e = blockIdx.x * 256 + threadIdx.x;
    if (e < ne) atomicAdd(&deg[dst[e]], 1);
}

__global__ __launch_bounds__(1024) void scan1_kernel(
    const int* __restrict__ deg, int* __restrict__ offsets,
    int* __restrict__ bsum, int n)
{
    __shared__ int wsum[16];
    const int tid = threadIdx.x, wid = tid >> 6, lane = tid & 63;
    int i = blockIdx.x * 1024 + tid;
    int val = (i < n) ? deg[i] : 0;
    int x = val;
#pragma unroll
    for (int off = 1; off < 64; off <<= 1) {
        int y = __shfl_up(x, off);
        if (lane >= off) x += y;
    }
    if (lane == 63) wsum[wid] = x;
    __syncthreads();
    if (tid < 16) {
        int w = wsum[tid];
#pragma unroll
        for (int off = 1; off < 16; off <<= 1) {
            int y = __shfl_up(w, off);
            if (tid >= off) w += y;
        }
        wsum[tid] = w;
    }
    __syncthreads();
    int incl = x + (wid ? wsum[wid - 1] : 0);
    if (i < n) offsets[i + 1] = incl;
    if (tid == 1023) bsum[blockIdx.x] = incl;
}

__global__ __launch_bounds__(256) void scan3_kernel(
    const int* __restrict__ deg, int* __restrict__ offsets,
    int* __restrict__ cursor, const int* __restrict__ bsum, int n, int nb)
{
    __shared__ int sx[64];
    const int tid = threadIdx.x;
    if (tid < 64) {
        int vv = (tid < nb) ? bsum[tid] : 0;
        int x = vv;
#pragma unroll
        for (int off = 1; off < 64; off <<= 1) {
            int y = __shfl_up(x, off);
            if (tid >= off) x += y;
        }
        sx[tid] = x - vv;   // exclusive prefix of block sums
    }
    __syncthreads();
    int i = blockIdx.x * 256 + tid;
    if (i >= n) return;
    int incl = offsets[i + 1] + sx[i >> 10];
    offsets[i + 1] = incl;
    cursor[i] = incl - deg[i];
    if (i == 0) offsets[0] = 0;
}

__global__ __launch_bounds__(256) void scatter_kernel(
    const int* __restrict__ src, const int* __restrict__ dst,
    int* __restrict__ cursor, int* __restrict__ csr_src, int ne)
{
    int e = blockIdx.x * 256 + threadIdx.x;
    if (e < ne) {
        int pos = atomicAdd(&cursor[dst[e]], 1);
        csr_src[pos] = src[e];
    }
}

// ---------------- fused attention + skip + ReLU ----------------
// One wave per node; 4 edge slots x 16 lanes; lane owns 8 dims (16B).
// 2-deep software pipeline per slot + rotating index prefetch.
// No running max: logits tiny by construction; clamp at 60.
__global__ __launch_bounds__(256) void attn_kernel(
    const short* __restrict__ qkvs, const int* __restrict__ offsets,
    const int* __restrict__ csr_src, short* __restrict__ hout, int nnodes)
{
    int node = (blockIdx.x * 256 + threadIdx.x) >> 6;
    if (node >= nnodes) return;
    const int lane = threadIdx.x & 63;
    const int grp = lane >> 4;        // edge slot 0..3
    const int g   = lane & 15;        // dims 8g..8g+7 (head = g/4)
    const float scale = 0.17677669529663687f; // 1/sqrt(32)

    const size_t nb = (size_t)node * QS;
    short8v q8 = *reinterpret_cast<const short8v*>(&qkvs[nb + g * 8]);
    float qf[8];
#pragma unroll
    for (int i = 0; i < 8; ++i) qf[i] = bf2f((unsigned short)q8[i]);

    int e0 = offsets[node], e1 = offsets[node + 1];
    float s = 0.f;
    float acc[8] = {0.f, 0.f, 0.f, 0.f, 0.f, 0.f, 0.f, 0.f};

    int e = e0 + grp;
    int i0 = (e < e1)     ? csr_src[e]     : 0;
    int i1 = (e + 4 < e1) ? csr_src[e + 4] : 0;

    for (; e + 4 < e1; e += 8) {
        int j0 = (e + 8  < e1) ? csr_src[e + 8]  : 0;   // prefetch next pair
        int j1 = (e + 12 < e1) ? csr_src[e + 12] : 0;
        const short* kp0 = &qkvs[(size_t)i0 * QS + 128 + g * 8];
        const short* kp1 = &qkvs[(size_t)i1 * QS + 128 + g * 8];
        short8v k0 = *reinterpret_cast<const short8v*>(kp0);
        short8v v0 = *reinterpret_cast<const short8v*>(kp0 + 128);
        short8v k1 = *reinterpret_cast<const short8v*>(kp1);
        short8v v1 = *reinterpret_cast<const short8v*>(kp1 + 128);
        float p0 = 0.f, p1 = 0.f;
#pragma unroll
        for (int i = 0; i < 8; ++i) {
            p0 += qf[i] * bf2f((unsigned short)k0[i]);
            p1 += qf[i] * bf2f((unsigned short)k1[i]);
        }
        p0 += __shfl_xor(p0, 1);  p1 += __shfl_xor(p1, 1);
        p0 += __shfl_xor(p0, 2);  p1 += __shfl_xor(p1, 2);
        float w0 = __expf(fminf(p0 * scale, 60.f));
        float w1 = __expf(fminf(p1 * scale, 60.f));
        s += w0 + w1;
#pragma unroll
        for (int i = 0; i < 8; ++i)
            acc[i] += w0 * bf2f((unsigned short)v0[i]) + w1 * bf2f((unsigned short)v1[i]);
        i0 = j0; i1 = j1;
    }
    if (e < e1) {
        const short* kp0 = &qkvs[(size_t)i0 * QS + 128 + g * 8];
        short8v k0 = *reinterpret_cast<const short8v*>(kp0);
        short8v v0 = *reinterpret_cast<const short8v*>(kp0 + 128);
        float p0 = 0.f;
#pragma unroll
        for (int i = 0; i < 8; ++i) p0 += qf[i] * bf2f((unsigned short)k0[i]);
        p0 += __shfl_xor(p0, 1);
        p0 += __shfl_xor(p0, 2);
        float w0 = __expf(fminf(p0 * scale, 60.f));
        s += w0;
#pragma unroll
        for (int i = 0; i < 8; ++i) acc[i] += w0 * bf2f((unsigned short)v0[i]);
    }

    // merge the 4 edge slots (once per node)
#pragma unroll
    for (int off = 16; off <= 32; off <<= 1) {
        s += __shfl_xor(s, off);
#pragma unroll
        for (int i = 0; i < 8; ++i) acc[i] += __shfl_xor(acc[i], off);
    }
    float inv = 1.f / (s + 1e-16f);
    short8v sk8 = *reinterpret_cast<const short8v*>(&qkvs[nb + 384 + g * 8]);
    short8v o;
#pragma unroll
    for (int i = 0; i < 8; ++i) {
        float ov = fmaxf(acc[i] * inv + bf2f((unsigned short)sk8[i]), 0.f);
        o[i] = (short)f2bf(ov);
    }
    *reinterpret_cast<short8v*>(&hout[(size_t)node * HID + g * 8]) = o;
}

// ---------------- pooling over sorted batch (bf16 h) ----------------
__global__ __launch_bounds__(256) void pool_kernel(
    const short* __restrict__ h, const int* __restrict__ batch,
    float* __restrict__ pooled, int nnodes)
{
    const int ROWS = 256;
    int n0 = blockIdx.x * ROWS;
    if (n0 >= nnodes) return;
    int n1 = min(n0 + ROWS, nnodes);
    int rg = threadIdx.x >> 4;      // 16 parallel row streams
    int c8 = threadIdx.x & 15;      // 8 cols each (16B loads)
    float s[8] = {0.f, 0.f, 0.f, 0.f, 0.f, 0.f, 0.f, 0.f};
    int g = -1;
    for (int n = n0 + rg; n < n1; n += 16) {
        int bg = batch[n];
        if (bg != g) {
            if (g >= 0) {
#pragma unroll
                for (int i = 0; i < 8; ++i) {
                    atomicAdd(&pooled[g * HID + c8 * 8 + i], s[i]);
                    s[i] = 0.f;
                }
            }
            g = bg;
        }
        short8v hv = *reinterpret_cast<const short8v*>(&h[(size_t)n * HID + c8 * 8]);
#pragma unroll
        for (int i = 0; i < 8; ++i) s[i] += bf2f((unsigned short)hv[i]);
    }
    if (g >= 0) {
#pragma unroll
        for (int i = 0; i < 8; ++i)
            atomicAdd(&pooled[g * HID + c8 * 8 + i], s[i]);
    }
}

// ---------------- final FC ----------------
__global__ __launch_bounds__(256) void fc_kernel(
    const float* __restrict__ pooled, const float* __restrict__ Wfc,
    const float* __restrict__ bfc, float* __restrict__ out)
{
    int t = blockIdx.x * 256 + threadIdx.x;   // 4096 = G*LAT
    if (t >= NG * LAT) return;
    int g = t >> 6, o = t & 63;
    float sum = bfc[o];
    for (int j = 0; j < HID; ++j)
        sum += pooled[g * HID + j] * Wfc[o * HID + j];
    out[t] = sum;
}

extern "C" void kernel_launch(void* const* d_in, const int* in_sizes, int n_in,
                              void* d_out, int out_size, void* d_ws, size_t ws_size,
                              hipStream_t stream)
{
    const float* x     = (const float*)d_in[0];
    const int*   ei    = (const int*)d_in[1];
    const int*   batch = (const int*)d_in[2];
    const float* Win   = (const float*)d_in[3];
    const float* bin_  = (const float*)d_in[4];
    const float* Wq    = (const float*)d_in[5];
    const float* bq    = (const float*)d_in[6];
    const float* Wk    = (const float*)d_in[7];
    const float* bk    = (const float*)d_in[8];
    const float* Wv    = (const float*)d_in[9];
    const float* bv    = (const float*)d_in[10];
    const float* Wskip = (const float*)d_in[11];
    const float* bskip = (const float*)d_in[12];
    const float* Wfc   = (const float*)d_in[13];
    const float* bfc   = (const float*)d_in[14];
    float* out = (float*)d_out;

    // workspace layout (~76 MB), 256B-aligned chunks
    char* ws = (char*)d_ws;
    auto alloc = [&](size_t bytes) {
        void* p = (void*)ws;
        ws += (bytes + 255) & ~(size_t)255;
        return p;
    };
    short* hb     = (short*)alloc((size_t)NN * HID * 2);
    short* qkvs   = (short*)alloc((size_t)NN * QS * 2);
    short* Wcat   = (short*)alloc((size_t)13 * 16384 * 2);
    float* bcat   = (float*)alloc((size_t)13 * 128 * 4);
    float* pooled = (float*)alloc((size_t)NG * HID * 4);
    int* deg      = (int*)alloc((size_t)NN * 4);
    int* offsets  = (int*)alloc((size_t)(NN + 1) * 4);
    int* cursor   = (int*)alloc((size_t)NN * 4);
    int* bsum     = (int*)alloc((size_t)64 * 4);
    int* csr_src  = (int*)alloc((size_t)NE * 4);

    const int* esrc = ei;
    const int* edst = ei + NE;

    PtrTab wt, bt;
    wt.p[0] = Win; bt.p[0] = bin_;
    for (int l = 0; l < NL; ++l) {
        wt.p[1 + 4 * l] = Wq    + (size_t)l * HID * HID;
        wt.p[2 + 4 * l] = Wk    + (size_t)l * HID * HID;
        wt.p[3 + 4 * l] = Wv    + (size_t)l * HID * HID;
        wt.p[4 + 4 * l] = Wskip + (size_t)l * HID * HID;
        bt.p[1 + 4 * l] = bq    + (size_t)l * HID;
        bt.p[2 + 4 * l] = bk    + (size_t)l * HID;
        bt.p[3 + 4 * l] = bv    + (size_t)l * HID;
        bt.p[4 + 4 * l] = bskip + (size_t)l * HID;
    }

    pack_all_kernel<<<(13 * 16384) / 256, 256, 0, stream>>>(wt, bt, Wcat, bcat, deg, pooled);

    const int egrid = (NE + 255) / 256;
    const int nsb = (NN + 1023) / 1024;   // 49
    count_deg_kernel<<<egrid, 256, 0, stream>>>(edst, deg, NE);
    scan1_kernel<<<nsb, 1024, 0, stream>>>(deg, offsets, bsum, NN);
    scan3_kernel<<<(NN + 255) / 256, 256, 0, stream>>>(deg, offsets, cursor, bsum, NN, nsb);
    scatter_kernel<<<egrid, 256, 0, stream>>>(esrc, edst, cursor, csr_src, NE);

    // input projection: h = x @ Win^T + bin (fp32 A converted on load)
    gemm_mfma<1, 1><<<(NN + 255) / 256, 256, 0, stream>>>(x, Wcat, bcat, hb, NN);

    const int g4 = (NN + 127) / 128;      // 391
    for (int l = 0; l < NL; ++l) {
        gemm_mfma<4, 0><<<g4, 512, 0, stream>>>(
            hb, Wcat + (size_t)(1 + 4 * l) * 16384, bcat + (1 + 4 * l) * 128, qkvs, NN);
        attn_kernel<<<(NN + 3) / 4, 256, 0, stream>>>(qkvs, offsets, csr_src, hb, NN);
    }

    pool_kernel<<<(NN + 255) / 256, 256, 0, stream>>>(hb, batch, pooled, NN);
    fc_kernel<<<16, 256, 0, stream>>>(pooled, Wfc, bfc, out);
}